// Round 1
// baseline (7480.748 us; speedup 1.0000x reference)
//
#include <hip/hip_runtime.h>
#include <hip/hip_bf16.h>

#define B_ 64
#define T_ 512
#define D_ 512
#define K_ 256
#define G3 1536   // 3*D

typedef __attribute__((ext_vector_type(8))) short sh8;   // 8 x bf16 bits (4 VGPR)
typedef __attribute__((ext_vector_type(4))) short sh4;
typedef __attribute__((ext_vector_type(4))) float fx4;
typedef __attribute__((ext_vector_type(4))) int   ix4;

__device__ __forceinline__ short f2bf(float x) {
  __hip_bfloat16 h = __float2bfloat16(x);
  union { __hip_bfloat16 h; short s; } u; u.h = h; return u.s;
}
__device__ __forceinline__ float sigm(float x) { return 1.f / (1.f + __expf(-x)); }

// ---------------- codebook squared norms (f64) ----------------
__global__ void k_cnorm(const float* __restrict__ cb, double* __restrict__ cn) {
  int c = threadIdx.x;
  if (c < K_) {
    double s = 0.0;
    for (int k = 0; k < D_; ++k) { double v = cb[c * D_ + k]; s += v * v; }
    cn[c] = s;
  }
}

// ---------------- code_gates = codebook @ w_ih.T + b_ih  [256,1536] ----------------
// grid (96, 4): 16-row j-tiles (LDS 32KB), 64-code c-tiles
__global__ __launch_bounds__(256) void k_cg(const float* __restrict__ cb,
                                            const float* __restrict__ wih,
                                            const float* __restrict__ bih,
                                            float* __restrict__ cg) {
  __shared__ float wl[16][512];
  int j0 = blockIdx.x * 16, c0 = blockIdx.y * 64;
  for (int v = threadIdx.x; v < 16 * 128; v += 256) {
    int r = v >> 7, q = v & 127;
    *(fx4*)&wl[r][q * 4] = *(const fx4*)&wih[(j0 + r) * D_ + q * 4];
  }
  __syncthreads();
  for (int p = threadIdx.x; p < 1024; p += 256) {
    int j = p >> 6, c = c0 + (p & 63);
    fx4 a = {0.f, 0.f, 0.f, 0.f};
    const float* cbr = &cb[c * D_];
    for (int q = 0; q < 128; ++q) {
      fx4 w4 = *(fx4*)&wl[j][q * 4];
      fx4 c4 = *(const fx4*)&cbr[q * 4];
      a += w4 * c4;
    }
    cg[c * G3 + j0 + j] = ((a.x + a.y) + (a.z + a.w)) + bih[j0 + j];
  }
}

// ---------------- f32 -> bf16 convert (proj_w) ----------------
__global__ void k_cvt(const float* __restrict__ src, __hip_bfloat16* __restrict__ dst, int n4) {
  int i = blockIdx.x * blockDim.x + threadIdx.x;
  if (i < n4) {
    fx4 v = *(const fx4*)&src[i * 4];
    sh4 o; o[0] = f2bf(v.x); o[1] = f2bf(v.y); o[2] = f2bf(v.z); o[3] = f2bf(v.w);
    *(sh4*)&dst[i * 4] = o;
  }
}

// ---------------- quantize: argmin over codes, exact-ties via f64 refine ----------------
// block: 16 rows x 16 code-groups (16 codes each). grid 2048.
__global__ __launch_bounds__(256) void k_quant(const float* __restrict__ feat,
                                               const float* __restrict__ cb,
                                               const double* __restrict__ cn,
                                               int* __restrict__ idxw,
                                               float* __restrict__ outq,
                                               float* __restrict__ outi) {
  __shared__ float fl[16][516];             // +4 pad: kills 16-way bank conflict
  __shared__ double ss1[16][16], ss2[16][16];
  __shared__ int ii1[16][16], ii2[16][16];
  __shared__ int idxl[16];
  int row0 = blockIdx.x * 16;
  int tid = threadIdx.x;
  for (int v = tid; v < 16 * 128; v += 256) {
    int r = v >> 7, q = v & 127;
    *(fx4*)&fl[r][q * 4] = *(const fx4*)&feat[(row0 + r) * D_ + q * 4];
  }
  __syncthreads();
  int r = tid & 15, g = tid >> 4;
  fx4 acc[16];
#pragma unroll
  for (int c = 0; c < 16; ++c) acc[c] = (fx4){0.f, 0.f, 0.f, 0.f};
  for (int ch = 0; ch < 8; ++ch) {          // 8 chunks of 64 dims
    fx4 fc[16];
#pragma unroll
    for (int q = 0; q < 16; ++q) fc[q] = *(fx4*)&fl[r][ch * 64 + q * 4];
#pragma unroll
    for (int c = 0; c < 16; ++c) {
      const float* cbp = &cb[(g * 16 + c) * D_ + ch * 64];
#pragma unroll
      for (int q = 0; q < 16; ++q) {
        fx4 c4 = *(const fx4*)&cbp[q * 4];
        acc[c] += fc[q] * c4;
      }
    }
  }
  double b1 = 1e300, b2 = 1e300; int i1 = 0, i2 = 0;
#pragma unroll
  for (int c = 0; c < 16; ++c) {
    int ci = g * 16 + c;
    double dot = (double)acc[c].x + acc[c].y + acc[c].z + acc[c].w;
    double s = cn[ci] - 2.0 * dot;          // ||f||^2 constant per row: argmin-equivalent
    if (s < b1) { b2 = b1; i2 = i1; b1 = s; i1 = ci; }
    else if (s < b2) { b2 = s; i2 = ci; }
  }
  ss1[r][g] = b1; ss2[r][g] = b2; ii1[r][g] = i1; ii2[r][g] = i2;
  __syncthreads();
  if (tid < 16) {
    int rr = tid;
    double c1 = 1e300, c2 = 1e300; int j1 = 0, j2 = 0;
    for (int g2 = 0; g2 < 16; ++g2) {
      double s = ss1[rr][g2]; int ix = ii1[rr][g2];
      if (s < c1 || (s == c1 && ix < j1)) { c2 = c1; j2 = j1; c1 = s; j1 = ix; }
      else if (s < c2 || (s == c2 && ix < j2)) { c2 = s; j2 = ix; }
      s = ss2[rr][g2]; ix = ii2[rr][g2];
      if (s < c1 || (s == c1 && ix < j1)) { c2 = c1; j2 = j1; c1 = s; j1 = ix; }
      else if (s < c2 || (s == c2 && ix < j2)) { c2 = s; j2 = ix; }
    }
    int pick = j1;
    if (c2 - c1 < 1e-4) {                   // near-tie: re-verify both in exact f64
      double d1 = 0.0, d2 = 0.0;
      for (int k = 0; k < D_; ++k) {
        double fv = fl[rr][k];
        d1 += fv * (double)cb[j1 * D_ + k];
        d2 += fv * (double)cb[j2 * D_ + k];
      }
      double e1 = cn[j1] - 2.0 * d1, e2 = cn[j2] - 2.0 * d2;
      if (e2 < e1 || (e2 == e1 && j2 < j1)) pick = j2;
    }
    idxl[rr] = pick;
    idxw[row0 + rr] = pick;
    outi[row0 + rr] = (float)pick;
  }
  __syncthreads();
  for (int v = tid; v < 16 * 128; v += 256) {   // gather quantized rows
    int rr = v >> 7, q = v & 127;
    *(fx4*)&outq[(row0 + rr) * D_ + q * 4] = *(const fx4*)&cb[idxl[rr] * D_ + q * 4];
  }
}

// ---------------- persistent GRU ----------------
// grid 64: group g = bid&7 (8 batch rows), slice s = bid>>3 (64 h-dims, 192 w_hh rows).
// w_hh slice lives in VGPRs as bf16 MFMA A-fragments. h exchanged via L2 + atomic barrier.
__global__ __launch_bounds__(256, 1) void k_gru(const float* __restrict__ whh,
                                                const float* __restrict__ bhh,
                                                const float* __restrict__ cg,
                                                const int* __restrict__ idx,
                                                __hip_bfloat16* __restrict__ hex,
                                                __hip_bfloat16* __restrict__ hid,
                                                unsigned int* __restrict__ bar) {
  int bid = blockIdx.x;
  int g = bid & 7, s = bid >> 3;
  int tid = threadIdx.x;
  int w = tid >> 6, lane = tid & 63, l15 = lane & 15, l4 = lane >> 4;

  // preload A fragments: wave w owns local rows [48w, 48w+48) of the 192-row slice
  sh8 A0[16], A1[16], A2[16];
#pragma unroll
  for (int kt = 0; kt < 16; ++kt) {
#pragma unroll
    for (int t3 = 0; t3 < 3; ++t3) {
      int lr = 48 * w + 16 * t3 + l15;
      int gate = lr >> 6, din = lr & 63;
      const float* wr = &whh[(gate * 512 + s * 64 + din) * D_];
      int k0 = kt * 32 + l4 * 8;
      fx4 x = *(const fx4*)&wr[k0];
      fx4 y = *(const fx4*)&wr[k0 + 4];
      sh8 t;
      t[0] = f2bf(x.x); t[1] = f2bf(x.y); t[2] = f2bf(x.z); t[3] = f2bf(x.w);
      t[4] = f2bf(y.x); t[5] = f2bf(y.y); t[6] = f2bf(y.z); t[7] = f2bf(y.w);
      if (t3 == 0) A0[kt] = t; else if (t3 == 1) A1[kt] = t; else A2[kt] = t;
    }
  }

  __shared__ float hl[8][64];      // f32 h (this group's batch x this wg's dims)
  __shared__ float hg[192][9];     // gate pre-activations (pad 9 vs 8: bank spread)
  __shared__ int ixs[8];
  for (int i = tid; i < 512; i += 256) ((float*)hl)[i] = 0.f;
  __syncthreads();

  for (int t = 0; t < T_; ++t) {
    int cur = t & 1, nxt = cur ^ 1;
    const __hip_bfloat16* hb = hex + (size_t)(cur * 8 + g) * 16 * 512;
    if (tid < 8) ixs[tid] = idx[(g * 8 + tid) * T_ + t];
    fx4 a0 = {0, 0, 0, 0}, a1 = {0, 0, 0, 0}, a2 = {0, 0, 0, 0};
#pragma unroll
    for (int kt = 0; kt < 16; ++kt) {
      sh8 bfr = *(const sh8*)&hb[l15 * 512 + kt * 32 + l4 * 8];
      a0 = __builtin_amdgcn_mfma_f32_16x16x32_bf16(A0[kt], bfr, a0, 0, 0, 0);
      a1 = __builtin_amdgcn_mfma_f32_16x16x32_bf16(A1[kt], bfr, a1, 0, 0, 0);
      a2 = __builtin_amdgcn_mfma_f32_16x16x32_bf16(A2[kt], bfr, a2, 0, 0, 0);
    }
    if (l15 < 8) {
#pragma unroll
      for (int rg = 0; rg < 4; ++rg) {
        hg[48 * w +      l4 * 4 + rg][l15] = a0[rg];
        hg[48 * w + 16 + l4 * 4 + rg][l15] = a1[rg];
        hg[48 * w + 32 + l4 * 4 + rg][l15] = a2[rg];
      }
    }
    __syncthreads();
#pragma unroll
    for (int ii = 0; ii < 2; ++ii) {
      int i = tid + ii * 256;
      int b = i >> 6, d = i & 63;
      int ci = ixs[b];
      const float* cgr = &cg[ci * G3 + s * 64 + d];
      int dg = s * 64 + d;
      float hr = hg[d][b]       + bhh[dg];
      float hz = hg[64 + d][b]  + bhh[512 + dg];
      float hn = hg[128 + d][b] + bhh[1024 + dg];
      float rr = sigm(cgr[0] + hr);
      float zz = sigm(cgr[512] + hz);
      float nn = tanhf(cgr[1024] + rr * hn);
      float hp = hl[b][d];
      float hv = (1.f - zz) * nn + zz * hp;
      hl[b][d] = hv;
      __hip_bfloat16 hb16 = __float2bfloat16(hv);
      hex[(size_t)((nxt * 8 + g) * 16 + b) * 512 + dg] = hb16;
      hid[(size_t)((g * 8 + b) * T_ + t) * D_ + dg] = hb16;
    }
    __threadfence();
    __syncthreads();
    if (tid == 0) {
      __hip_atomic_fetch_add(&bar[g], 1u, __ATOMIC_RELEASE, __HIP_MEMORY_SCOPE_AGENT);
      unsigned tgt = 8u * (unsigned)(t + 1);
      while (__hip_atomic_load(&bar[g], __ATOMIC_ACQUIRE, __HIP_MEMORY_SCOPE_AGENT) < tgt) {
        __builtin_amdgcn_s_sleep(1);
      }
    }
    __syncthreads();
    __threadfence();
  }
}

// ---------------- proj GEMM (bf16 MFMA) with fused cp_loss epilogue ----------------
// grid 1024: 32-row M-tiles, full N=512. BK=32 K-chunks staged in LDS (XOR swizzle).
__global__ __launch_bounds__(256) void k_proj(const __hip_bfloat16* __restrict__ hid,
                                              const __hip_bfloat16* __restrict__ pwb,
                                              const float* __restrict__ pb,
                                              const float* __restrict__ feat,
                                              double* __restrict__ lacc) {
  __shared__ char Bl[512 * 64];   // [512 n][32 k] bf16, 64B rows, swizzled
  __shared__ char Al[32 * 64];
  __shared__ float rs1[4], rs2[4];
  int Mb = blockIdx.x * 32;
  int tid = threadIdx.x;
  int w = tid >> 6, lane = tid & 63, l15 = lane & 15, l4 = lane >> 4;
  fx4 acc[2][8];
#pragma unroll
  for (int a = 0; a < 2; ++a)
#pragma unroll
    for (int b = 0; b < 8; ++b) acc[a][b] = (fx4){0, 0, 0, 0};

  for (int kc = 0; kc < 16; ++kc) {
    for (int v = tid; v < 2048; v += 256) {
      int rw = v >> 2, sg = v & 3;
      ix4 d = *(const ix4*)&pwb[rw * D_ + kc * 32 + sg * 8];
      *(ix4*)(Bl + rw * 64 + ((sg * 16) ^ ((rw & 7) << 4))) = d;
    }
    if (tid < 128) {
      int rw = tid >> 2, sg = tid & 3;
      ix4 d = *(const ix4*)&hid[(size_t)(Mb + rw) * D_ + kc * 32 + sg * 8];
      *(ix4*)(Al + rw * 64 + ((sg * 16) ^ ((rw & 7) << 4))) = d;
    }
    __syncthreads();
    sh8 af0, af1;
    {
      int m = l15;
      af0 = *(const sh8*)(Al + m * 64 + ((l4 * 16) ^ ((m & 7) << 4)));
      m = 16 + l15;
      af1 = *(const sh8*)(Al + m * 64 + ((l4 * 16) ^ ((m & 7) << 4)));
    }
#pragma unroll
    for (int nt = 0; nt < 8; ++nt) {
      int n = (w * 8 + nt) * 16 + l15;
      sh8 bf = *(const sh8*)(Bl + n * 64 + ((l4 * 16) ^ ((n & 7) << 4)));
      acc[0][nt] = __builtin_amdgcn_mfma_f32_16x16x32_bf16(af0, bf, acc[0][nt], 0, 0, 0);
      acc[1][nt] = __builtin_amdgcn_mfma_f32_16x16x32_bf16(af1, bf, acc[1][nt], 0, 0, 0);
    }
    __syncthreads();
  }

  float s1 = 0.f, s2 = 0.f;
#pragma unroll
  for (int mt = 0; mt < 2; ++mt) {
#pragma unroll
    for (int nt = 0; nt < 8; ++nt) {
      int n = (w * 8 + nt) * 16 + l15;
      float bias = pb[n];
#pragma unroll
      for (int rg = 0; rg < 4; ++rg) {
        int m = Mb + mt * 16 + l4 * 4 + rg;
        float val = acc[mt][nt][rg] + bias;
        int t = m & (T_ - 1);
        if (t < T_ - 1) { float d = val - feat[(size_t)(m + 1) * D_ + n]; s1 += d * d; }
        if (t < T_ - 2) { float d = val - feat[(size_t)(m + 2) * D_ + n]; s2 += d * d; }
      }
    }
  }
#pragma unroll
  for (int off = 32; off > 0; off >>= 1) {
    s1 += __shfl_down(s1, off);
    s2 += __shfl_down(s2, off);
  }
  if (lane == 0) { rs1[w] = s1; rs2[w] = s2; }
  __syncthreads();
  if (tid == 0) {
    atomicAdd(&lacc[0], (double)rs1[0] + rs1[1] + rs1[2] + rs1[3]);
    atomicAdd(&lacc[1], (double)rs2[0] + rs2[1] + rs2[2] + rs2[3]);
  }
}

// ---------------- vq loss reduction ----------------
__global__ __launch_bounds__(256) void k_vq(const float* __restrict__ f,
                                            const float* __restrict__ q,
                                            double* __restrict__ lacc) {
  const int n4 = B_ * T_ * D_ / 4;
  float s = 0.f;
  for (int i = blockIdx.x * blockDim.x + threadIdx.x; i < n4; i += gridDim.x * blockDim.x) {
    fx4 a = *(const fx4*)&f[i * 4];
    fx4 b = *(const fx4*)&q[i * 4];
    fx4 d = a - b;
    s += d.x * d.x + d.y * d.y + d.z * d.z + d.w * d.w;
  }
#pragma unroll
  for (int off = 32; off > 0; off >>= 1) s += __shfl_down(s, off);
  __shared__ float rs[4];
  int w = threadIdx.x >> 6;
  if ((threadIdx.x & 63) == 0) rs[w] = s;
  __syncthreads();
  if (threadIdx.x == 0) atomicAdd(&lacc[2], (double)(rs[0] + rs[1] + rs[2] + rs[3]));
}

// ---------------- finalize losses ----------------
__global__ void k_fin(const double* __restrict__ lacc, float* __restrict__ outl) {
  if (threadIdx.x == 0) {
    double cp = 0.5 * (lacc[0] / ((double)B_ * (T_ - 1) * D_) +
                       lacc[1] / ((double)B_ * (T_ - 2) * D_));
    double vq = 1.25 * lacc[2] / ((double)B_ * T_ * D_);
    outl[0] = (float)(cp + vq);
    outl[1] = (float)cp;
    outl[2] = (float)vq;
  }
}

extern "C" void kernel_launch(void* const* d_in, const int* in_sizes, int n_in,
                              void* d_out, int out_size, void* d_ws, size_t ws_size,
                              hipStream_t stream) {
  (void)in_sizes; (void)n_in; (void)out_size; (void)ws_size;
  const float* feat = (const float*)d_in[0];
  const float* cb   = (const float*)d_in[1];
  const float* wih  = (const float*)d_in[2];
  const float* whh  = (const float*)d_in[3];
  const float* bih  = (const float*)d_in[4];
  const float* bhh  = (const float*)d_in[5];
  const float* pw   = (const float*)d_in[6];
  const float* pb   = (const float*)d_in[7];

  float* out  = (float*)d_out;
  float* outq = out;
  float* outi = out + (size_t)B_ * T_ * D_;
  float* outl = outi + B_ * T_;

  char* ws = (char*)d_ws;
  size_t o = 0;
  auto alloc = [&](size_t sz) { void* p = ws + o; o += (sz + 255) & ~(size_t)255; return p; };
  float*          cg   = (float*)alloc(sizeof(float) * K_ * G3);
  double*         cn   = (double*)alloc(sizeof(double) * K_);
  int*            idxw = (int*)alloc(sizeof(int) * B_ * T_);
  __hip_bfloat16* pwb  = (__hip_bfloat16*)alloc(sizeof(__hip_bfloat16) * D_ * D_);
  __hip_bfloat16* hex  = (__hip_bfloat16*)alloc(sizeof(__hip_bfloat16) * 2 * 8 * 16 * 512);
  double*         lacc = (double*)alloc(sizeof(double) * 4);
  unsigned*       bar  = (unsigned*)alloc(sizeof(unsigned) * 8);
  __hip_bfloat16* hid  = (__hip_bfloat16*)alloc(sizeof(__hip_bfloat16) * (size_t)B_ * T_ * D_);

  hipMemsetAsync(hex, 0, sizeof(__hip_bfloat16) * 2 * 8 * 16 * 512, stream);
  hipMemsetAsync(lacc, 0, sizeof(double) * 4, stream);
  hipMemsetAsync(bar, 0, sizeof(unsigned) * 8, stream);

  hipLaunchKernelGGL(k_cnorm, dim3(1), dim3(256), 0, stream, cb, cn);
  hipLaunchKernelGGL(k_cg, dim3(96, 4), dim3(256), 0, stream, cb, wih, bih, cg);
  hipLaunchKernelGGL(k_cvt, dim3(256), dim3(256), 0, stream, pw, pwb, D_ * D_ / 4);
  hipLaunchKernelGGL(k_quant, dim3(2048), dim3(256), 0, stream, feat, cb, cn, idxw, outq, outi);
  hipLaunchKernelGGL(k_gru, dim3(64), dim3(256), 0, stream, whh, bhh, cg, idxw, hex, hid, bar);
  hipLaunchKernelGGL(k_proj, dim3(1024), dim3(256), 0, stream, hid, pwb, pb, feat, lacc);
  hipLaunchKernelGGL(k_vq, dim3(2048), dim3(256), 0, stream, feat, outq, lacc);
  hipLaunchKernelGGL(k_fin, dim3(1), dim3(64), 0, stream, lacc, outl);
}

// Round 2
// 2946.779 us; speedup vs baseline: 2.5386x; 2.5386x over previous
//
#include <hip/hip_runtime.h>
#include <hip/hip_bf16.h>

#define B_ 64
#define T_ 512
#define D_ 512
#define K_ 256
#define G3 1536   // 3*D

typedef __attribute__((ext_vector_type(8))) short sh8;   // 8 x bf16 bits (4 VGPR)
typedef __attribute__((ext_vector_type(4))) short sh4;
typedef __attribute__((ext_vector_type(4))) float fx4;
typedef __attribute__((ext_vector_type(4))) int   ix4;

__device__ __forceinline__ short f2bf(float x) {
  __hip_bfloat16 h = __float2bfloat16(x);
  union { __hip_bfloat16 h; short s; } u; u.h = h; return u.s;
}
__device__ __forceinline__ float sigm(float x) { return 1.f / (1.f + __expf(-x)); }

// ---------------- codebook squared norms (f64) ----------------
__global__ void k_cnorm(const float* __restrict__ cb, double* __restrict__ cn) {
  int c = threadIdx.x;
  if (c < K_) {
    double s = 0.0;
    for (int k = 0; k < D_; ++k) { double v = cb[c * D_ + k]; s += v * v; }
    cn[c] = s;
  }
}

// ---------------- code_gates = codebook @ w_ih.T + b_ih  [256,1536] ----------------
__global__ __launch_bounds__(256) void k_cg(const float* __restrict__ cb,
                                            const float* __restrict__ wih,
                                            const float* __restrict__ bih,
                                            float* __restrict__ cg) {
  __shared__ float wl[16][512];
  int j0 = blockIdx.x * 16, c0 = blockIdx.y * 64;
  for (int v = threadIdx.x; v < 16 * 128; v += 256) {
    int r = v >> 7, q = v & 127;
    *(fx4*)&wl[r][q * 4] = *(const fx4*)&wih[(j0 + r) * D_ + q * 4];
  }
  __syncthreads();
  for (int p = threadIdx.x; p < 1024; p += 256) {
    int j = p >> 6, c = c0 + (p & 63);
    fx4 a = {0.f, 0.f, 0.f, 0.f};
    const float* cbr = &cb[c * D_];
    for (int q = 0; q < 128; ++q) {
      fx4 w4 = *(fx4*)&wl[j][q * 4];
      fx4 c4 = *(const fx4*)&cbr[q * 4];
      a += w4 * c4;
    }
    cg[c * G3 + j0 + j] = ((a.x + a.y) + (a.z + a.w)) + bih[j0 + j];
  }
}

// ---------------- f32 -> bf16 convert (proj_w) ----------------
__global__ void k_cvt(const float* __restrict__ src, __hip_bfloat16* __restrict__ dst, int n4) {
  int i = blockIdx.x * blockDim.x + threadIdx.x;
  if (i < n4) {
    fx4 v = *(const fx4*)&src[i * 4];
    sh4 o; o[0] = f2bf(v.x); o[1] = f2bf(v.y); o[2] = f2bf(v.z); o[3] = f2bf(v.w);
    *(sh4*)&dst[i * 4] = o;
  }
}

// ---------------- quantize: argmin + fused vq-loss partial ----------------
__global__ __launch_bounds__(256) void k_quant(const float* __restrict__ feat,
                                               const float* __restrict__ cb,
                                               const double* __restrict__ cn,
                                               int* __restrict__ idxw,
                                               float* __restrict__ outq,
                                               float* __restrict__ outi,
                                               double* __restrict__ lacc) {
  __shared__ float fl[16][516];             // +4 pad: kills 16-way bank conflict
  __shared__ double ss1[16][16], ss2[16][16];
  __shared__ int ii1[16][16], ii2[16][16];
  __shared__ int idxl[16];
  __shared__ float rsv[4];
  int row0 = blockIdx.x * 16;
  int tid = threadIdx.x;
  for (int v = tid; v < 16 * 128; v += 256) {
    int r = v >> 7, q = v & 127;
    *(fx4*)&fl[r][q * 4] = *(const fx4*)&feat[(row0 + r) * D_ + q * 4];
  }
  __syncthreads();
  int r = tid & 15, g = tid >> 4;
  fx4 acc[16];
#pragma unroll
  for (int c = 0; c < 16; ++c) acc[c] = (fx4){0.f, 0.f, 0.f, 0.f};
  for (int ch = 0; ch < 8; ++ch) {          // 8 chunks of 64 dims
    fx4 fc[16];
#pragma unroll
    for (int q = 0; q < 16; ++q) fc[q] = *(fx4*)&fl[r][ch * 64 + q * 4];
#pragma unroll
    for (int c = 0; c < 16; ++c) {
      const float* cbp = &cb[(g * 16 + c) * D_ + ch * 64];
#pragma unroll
      for (int q = 0; q < 16; ++q) {
        fx4 c4 = *(const fx4*)&cbp[q * 4];
        acc[c] += fc[q] * c4;
      }
    }
  }
  double b1 = 1e300, b2 = 1e300; int i1 = 0, i2 = 0;
#pragma unroll
  for (int c = 0; c < 16; ++c) {
    int ci = g * 16 + c;
    double dot = (double)acc[c].x + acc[c].y + acc[c].z + acc[c].w;
    double s = cn[ci] - 2.0 * dot;
    if (s < b1) { b2 = b1; i2 = i1; b1 = s; i1 = ci; }
    else if (s < b2) { b2 = s; i2 = ci; }
  }
  ss1[r][g] = b1; ss2[r][g] = b2; ii1[r][g] = i1; ii2[r][g] = i2;
  __syncthreads();
  if (tid < 16) {
    int rr = tid;
    double c1 = 1e300, c2 = 1e300; int j1 = 0, j2 = 0;
    for (int g2 = 0; g2 < 16; ++g2) {
      double s = ss1[rr][g2]; int ix = ii1[rr][g2];
      if (s < c1 || (s == c1 && ix < j1)) { c2 = c1; j2 = j1; c1 = s; j1 = ix; }
      else if (s < c2 || (s == c2 && ix < j2)) { c2 = s; j2 = ix; }
      s = ss2[rr][g2]; ix = ii2[rr][g2];
      if (s < c1 || (s == c1 && ix < j1)) { c2 = c1; j2 = j1; c1 = s; j1 = ix; }
      else if (s < c2 || (s == c2 && ix < j2)) { c2 = s; j2 = ix; }
    }
    int pick = j1;
    if (c2 - c1 < 1e-4) {                   // near-tie: re-verify both in exact f64
      double d1 = 0.0, d2 = 0.0;
      for (int k = 0; k < D_; ++k) {
        double fv = fl[rr][k];
        d1 += fv * (double)cb[j1 * D_ + k];
        d2 += fv * (double)cb[j2 * D_ + k];
      }
      double e1 = cn[j1] - 2.0 * d1, e2 = cn[j2] - 2.0 * d2;
      if (e2 < e1 || (e2 == e1 && j2 < j1)) pick = j2;
    }
    idxl[rr] = pick;
    idxw[row0 + rr] = pick;
    outi[row0 + rr] = (float)pick;
  }
  __syncthreads();
  float vs = 0.f;
  for (int v = tid; v < 16 * 128; v += 256) {   // gather quantized + vq partial
    int rr = v >> 7, q = v & 127;
    fx4 c4 = *(const fx4*)&cb[idxl[rr] * D_ + q * 4];
    *(fx4*)&outq[(row0 + rr) * D_ + q * 4] = c4;
    fx4 f4 = *(fx4*)&fl[rr][q * 4];
    fx4 d = f4 - c4;
    vs += d.x * d.x + d.y * d.y + d.z * d.z + d.w * d.w;
  }
#pragma unroll
  for (int off = 32; off > 0; off >>= 1) vs += __shfl_down(vs, off);
  if ((tid & 63) == 0) rsv[tid >> 6] = vs;
  __syncthreads();
  if (tid == 0) atomicAdd(&lacc[2], (double)(rsv[0] + rsv[1] + rsv[2] + rsv[3]));
}

// ---------------- persistent GRU ----------------
// grid 64: group g = bid&7 (8 batch rows, one XCD if round-robin), slice s = bid>>3.
// Same-XCD fast path: no fences, relaxed per-block flags through shared L2;
// exchange via hid[b][t][d] (fresh address each step -> no stale L1).
// Fallback (placement check fails): fenced protocol, still correct.
__global__ __launch_bounds__(256, 1) void k_gru(const float* __restrict__ whh,
                                                const float* __restrict__ bhh,
                                                const float* __restrict__ cg,
                                                const int* __restrict__ idx,
                                                __hip_bfloat16* __restrict__ hid,
                                                unsigned int* __restrict__ flag,
                                                int* __restrict__ xcca,
                                                unsigned int* __restrict__ bar0) {
  int bid = blockIdx.x;
  int g = bid & 7, s = bid >> 3;
  int tid = threadIdx.x;
  int w = tid >> 6, lane = tid & 63, l15 = lane & 15, l4 = lane >> 4;

  // preload A fragments: wave w owns local rows [48w, 48w+48) of the 192-row slice
  sh8 A0[16], A1[16], A2[16];
#pragma unroll
  for (int kt = 0; kt < 16; ++kt) {
#pragma unroll
    for (int t3 = 0; t3 < 3; ++t3) {
      int lr = 48 * w + 16 * t3 + l15;
      int gate = lr >> 6, din = lr & 63;
      const float* wr = &whh[(gate * 512 + s * 64 + din) * D_];
      int k0 = kt * 32 + l4 * 8;
      fx4 x = *(const fx4*)&wr[k0];
      fx4 y = *(const fx4*)&wr[k0 + 4];
      sh8 t;
      t[0] = f2bf(x.x); t[1] = f2bf(x.y); t[2] = f2bf(x.z); t[3] = f2bf(x.w);
      t[4] = f2bf(y.x); t[5] = f2bf(y.y); t[6] = f2bf(y.z); t[7] = f2bf(y.w);
      if (t3 == 0) A0[kt] = t; else if (t3 == 1) A1[kt] = t; else A2[kt] = t;
    }
  }

  __shared__ float hl[8][64];      // f32 h (this group's batch x this wg's dims)
  __shared__ float hg[192][9];     // gate pre-activations (pad 9: bank spread)
  __shared__ int ixs[8];
  __shared__ int sh_fast;
  for (int i = tid; i < 512; i += 256) ((float*)hl)[i] = 0.f;

  // -------- one-time placement handshake (heavyweight, correct anywhere) -----
  if (tid == 0) {
    int xcc = 0;
    asm volatile("s_getreg_b32 %0, hwreg(HW_REG_XCC_ID)" : "=s"(xcc));
    __hip_atomic_store(&xcca[bid], xcc, __ATOMIC_RELEASE, __HIP_MEMORY_SCOPE_AGENT);
    __hip_atomic_fetch_add(bar0, 1u, __ATOMIC_ACQ_REL, __HIP_MEMORY_SCOPE_AGENT);
    while (__hip_atomic_load(bar0, __ATOMIC_ACQUIRE, __HIP_MEMORY_SCOPE_AGENT) < 64u)
      __builtin_amdgcn_s_sleep(2);
    int x0 = __hip_atomic_load(&xcca[g], __ATOMIC_RELAXED, __HIP_MEMORY_SCOPE_AGENT);
    int f = 1;
    for (int m = 1; m < 8; ++m)
      if (__hip_atomic_load(&xcca[g + 8 * m], __ATOMIC_RELAXED, __HIP_MEMORY_SCOPE_AGENT) != x0)
        f = 0;
    sh_fast = f;
  }
  __syncthreads();
  const bool fast = (sh_fast != 0);

  for (int t = 0; t < T_; ++t) {
    if (tid < 8) ixs[tid] = idx[(g * 8 + tid) * T_ + t];

    fx4 a0 = {0, 0, 0, 0}, a1 = {0, 0, 0, 0}, a2 = {0, 0, 0, 0};
    if (t > 0) {
      // wait: all group members published step t-1
      if (tid < 8) {
        while (__hip_atomic_load(&flag[tid * 8 + g], __ATOMIC_RELAXED,
                                 __HIP_MEMORY_SCOPE_AGENT) < (unsigned)t)
          __builtin_amdgcn_s_sleep(1);
      }
      if (!fast && tid == 0) __threadfence();   // acquire: L2 invalidate (cross-XCD)
      __syncthreads();

      const __hip_bfloat16* hrow =
          &hid[((size_t)(g * 8 + (l15 & 7)) * T_ + (t - 1)) * D_];
#pragma unroll
      for (int kt = 0; kt < 16; ++kt) {
        sh8 bfr = {0, 0, 0, 0, 0, 0, 0, 0};
        if (l15 < 8) bfr = *(const sh8*)&hrow[kt * 32 + l4 * 8];
        a0 = __builtin_amdgcn_mfma_f32_16x16x32_bf16(A0[kt], bfr, a0, 0, 0, 0);
        a1 = __builtin_amdgcn_mfma_f32_16x16x32_bf16(A1[kt], bfr, a1, 0, 0, 0);
        a2 = __builtin_amdgcn_mfma_f32_16x16x32_bf16(A2[kt], bfr, a2, 0, 0, 0);
      }
    }
    if (l15 < 8) {
#pragma unroll
      for (int rg = 0; rg < 4; ++rg) {
        hg[48 * w +      l4 * 4 + rg][l15] = a0[rg];
        hg[48 * w + 16 + l4 * 4 + rg][l15] = a1[rg];
        hg[48 * w + 32 + l4 * 4 + rg][l15] = a2[rg];
      }
    }
    __syncthreads();
#pragma unroll
    for (int ii = 0; ii < 2; ++ii) {
      int i = tid + ii * 256;
      int b = i >> 6, d = i & 63;
      int ci = ixs[b];
      const float* cgr = &cg[ci * G3 + s * 64 + d];
      int dg = s * 64 + d;
      float hr = hg[d][b]       + bhh[dg];
      float hz = hg[64 + d][b]  + bhh[512 + dg];
      float hn = hg[128 + d][b] + bhh[1024 + dg];
      float rr = sigm(cgr[0] + hr);
      float zz = sigm(cgr[512] + hz);
      float nn = tanhf(cgr[1024] + rr * hn);
      float hp = hl[b][d];
      float hv = (1.f - zz) * nn + zz * hp;
      hl[b][d] = hv;
      hid[((size_t)(g * 8 + b) * T_ + t) * D_ + dg] = __float2bfloat16(hv);
    }
    __syncthreads();   // compiler drains vmcnt(0) before s_barrier: stores in L2
    if (tid == 0) {
      if (!fast) __threadfence();             // release: L2 writeback (cross-XCD)
      __hip_atomic_store(&flag[bid], (unsigned)(t + 1), __ATOMIC_RELAXED,
                         __HIP_MEMORY_SCOPE_AGENT);
    }
  }
}

// ---------------- proj GEMM (bf16 MFMA) with fused cp_loss epilogue ----------------
__global__ __launch_bounds__(256) void k_proj(const __hip_bfloat16* __restrict__ hid,
                                              const __hip_bfloat16* __restrict__ pwb,
                                              const float* __restrict__ pb,
                                              const float* __restrict__ feat,
                                              double* __restrict__ lacc) {
  __shared__ char Bl[512 * 64];   // [512 n][32 k] bf16, 64B rows, swizzled
  __shared__ char Al[32 * 64];
  __shared__ float rs1[4], rs2[4];
  int Mb = blockIdx.x * 32;
  int tid = threadIdx.x;
  int w = tid >> 6, lane = tid & 63, l15 = lane & 15, l4 = lane >> 4;
  fx4 acc[2][8];
#pragma unroll
  for (int a = 0; a < 2; ++a)
#pragma unroll
    for (int b = 0; b < 8; ++b) acc[a][b] = (fx4){0, 0, 0, 0};

  for (int kc = 0; kc < 16; ++kc) {
    for (int v = tid; v < 2048; v += 256) {
      int rw = v >> 2, sg = v & 3;
      ix4 d = *(const ix4*)&pwb[rw * D_ + kc * 32 + sg * 8];
      *(ix4*)(Bl + rw * 64 + ((sg * 16) ^ ((rw & 7) << 4))) = d;
    }
    if (tid < 128) {
      int rw = tid >> 2, sg = tid & 3;
      ix4 d = *(const ix4*)&hid[(size_t)(Mb + rw) * D_ + kc * 32 + sg * 8];
      *(ix4*)(Al + rw * 64 + ((sg * 16) ^ ((rw & 7) << 4))) = d;
    }
    __syncthreads();
    sh8 af0, af1;
    {
      int m = l15;
      af0 = *(const sh8*)(Al + m * 64 + ((l4 * 16) ^ ((m & 7) << 4)));
      m = 16 + l15;
      af1 = *(const sh8*)(Al + m * 64 + ((l4 * 16) ^ ((m & 7) << 4)));
    }
#pragma unroll
    for (int nt = 0; nt < 8; ++nt) {
      int n = (w * 8 + nt) * 16 + l15;
      sh8 bf = *(const sh8*)(Bl + n * 64 + ((l4 * 16) ^ ((n & 7) << 4)));
      acc[0][nt] = __builtin_amdgcn_mfma_f32_16x16x32_bf16(af0, bf, acc[0][nt], 0, 0, 0);
      acc[1][nt] = __builtin_amdgcn_mfma_f32_16x16x32_bf16(af1, bf, acc[1][nt], 0, 0, 0);
    }
    __syncthreads();
  }

  float s1 = 0.f, s2 = 0.f;
#pragma unroll
  for (int mt = 0; mt < 2; ++mt) {
#pragma unroll
    for (int nt = 0; nt < 8; ++nt) {
      int n = (w * 8 + nt) * 16 + l15;
      float bias = pb[n];
#pragma unroll
      for (int rg = 0; rg < 4; ++rg) {
        int m = Mb + mt * 16 + l4 * 4 + rg;
        float val = acc[mt][nt][rg] + bias;
        int t = m & (T_ - 1);
        if (t < T_ - 1) { float d = val - feat[(size_t)(m + 1) * D_ + n]; s1 += d * d; }
        if (t < T_ - 2) { float d = val - feat[(size_t)(m + 2) * D_ + n]; s2 += d * d; }
      }
    }
  }
#pragma unroll
  for (int off = 32; off > 0; off >>= 1) {
    s1 += __shfl_down(s1, off);
    s2 += __shfl_down(s2, off);
  }
  if (lane == 0) { rs1[w] = s1; rs2[w] = s2; }
  __syncthreads();
  if (tid == 0) {
    atomicAdd(&lacc[0], (double)rs1[0] + rs1[1] + rs1[2] + rs1[3]);
    atomicAdd(&lacc[1], (double)rs2[0] + rs2[1] + rs2[2] + rs2[3]);
  }
}

// ---------------- finalize losses ----------------
__global__ void k_fin(const double* __restrict__ lacc, float* __restrict__ outl) {
  if (threadIdx.x == 0) {
    double cp = 0.5 * (lacc[0] / ((double)B_ * (T_ - 1) * D_) +
                       lacc[1] / ((double)B_ * (T_ - 2) * D_));
    double vq = 1.25 * lacc[2] / ((double)B_ * T_ * D_);
    outl[0] = (float)(cp + vq);
    outl[1] = (float)cp;
    outl[2] = (float)vq;
  }
}

extern "C" void kernel_launch(void* const* d_in, const int* in_sizes, int n_in,
                              void* d_out, int out_size, void* d_ws, size_t ws_size,
                              hipStream_t stream) {
  (void)in_sizes; (void)n_in; (void)out_size; (void)ws_size;
  const float* feat = (const float*)d_in[0];
  const float* cb   = (const float*)d_in[1];
  const float* wih  = (const float*)d_in[2];
  const float* whh  = (const float*)d_in[3];
  const float* bih  = (const float*)d_in[4];
  const float* bhh  = (const float*)d_in[5];
  const float* pw   = (const float*)d_in[6];
  const float* pb   = (const float*)d_in[7];

  float* out  = (float*)d_out;
  float* outq = out;
  float* outi = out + (size_t)B_ * T_ * D_;
  float* outl = outi + B_ * T_;

  char* ws = (char*)d_ws;
  size_t o = 0;
  auto alloc = [&](size_t sz) { void* p = ws + o; o += (sz + 255) & ~(size_t)255; return p; };
  float*          cg   = (float*)alloc(sizeof(float) * K_ * G3);
  double*         cn   = (double*)alloc(sizeof(double) * K_);
  int*            idxw = (int*)alloc(sizeof(int) * B_ * T_);
  __hip_bfloat16* pwb  = (__hip_bfloat16*)alloc(sizeof(__hip_bfloat16) * D_ * D_);
  double*         lacc = (double*)alloc(sizeof(double) * 4);
  unsigned*       flag = (unsigned*)alloc(sizeof(unsigned) * 64);
  int*            xcca = (int*)alloc(sizeof(int) * 64);
  unsigned*       bar0 = (unsigned*)alloc(sizeof(unsigned) * 4);
  __hip_bfloat16* hid  = (__hip_bfloat16*)alloc(sizeof(__hip_bfloat16) * (size_t)B_ * T_ * D_);

  hipMemsetAsync(lacc, 0, sizeof(double) * 4, stream);
  hipMemsetAsync(flag, 0, sizeof(unsigned) * 64, stream);
  hipMemsetAsync(xcca, 0, sizeof(int) * 64, stream);
  hipMemsetAsync(bar0, 0, sizeof(unsigned) * 4, stream);

  hipLaunchKernelGGL(k_cnorm, dim3(1), dim3(256), 0, stream, cb, cn);
  hipLaunchKernelGGL(k_cg, dim3(96, 4), dim3(256), 0, stream, cb, wih, bih, cg);
  hipLaunchKernelGGL(k_cvt, dim3(256), dim3(256), 0, stream, pw, pwb, D_ * D_ / 4);
  hipLaunchKernelGGL(k_quant, dim3(2048), dim3(256), 0, stream, feat, cb, cn, idxw, outq, outi, lacc);
  hipLaunchKernelGGL(k_gru, dim3(64), dim3(256), 0, stream, whh, bhh, cg, idxw, hid, flag, xcca, bar0);
  hipLaunchKernelGGL(k_proj, dim3(1024), dim3(256), 0, stream, hid, pwb, pb, feat, lacc);
  hipLaunchKernelGGL(k_fin, dim3(1), dim3(64), 0, stream, lacc, outl);
}